// Round 5
// baseline (317.575 us; speedup 1.0000x reference)
//
#include <hip/hip_runtime.h>

#define IMW 1024
#define IMH 1024
#define NB  8
#define HALF 25
#define STRIP 32
#define NCELL 64

#define W_R ((double)0.2989f)
#define W_G ((double)0.5870f)
#define W_B ((double)0.1140f)
#define INV_AREA (1.0 / 2601.0)

__device__ __forceinline__ int refl(int i, int n) {
    if (i < 0) i = -i;
    if (i >= n) i = 2 * n - 2 - i;
    return i;
}

// LDS swizzle: +1 slot per 32 entries. Stride-4 f32 reads (lane t -> 4t+c):
// bank = (4t + c + (4t+c)/32) mod 32 -> exactly 2 lanes/bank over 64 lanes,
// and 2-way is free on CDNA4 (m136). Injective, max swz(1023)=1054.
__device__ __forceinline__ int swz(int p) { return p + (p >> 5); }

// init 64 min-cells (all-ones) and 64 max-cells (zero); g>=0 so f32 bit-order == uint order
__global__ void k0_init(unsigned* cells) {
    cells[threadIdx.x] = (threadIdx.x < NCELL) ? 0xFFFFFFFFu : 0u;
}

// Block-per-row horizontal pass, scan-free. Thread t owns pixels 4t..4t+3.
// RGB in: 3 dense float4/lane. gray out: 1 dense float4/lane. Window sums via
// 51-tap f64 prologue (3 independent accumulators, ILP) + 3-step slide with
// exact f32 squares -- the numerics that passed (absmax 0) in rounds 1-4.
// One barrier (LDS gray staging crosses wave boundaries at the +/-25 halo).
// No shuffle scan, no f64 shuffles, no wsum branches.
__global__ __launch_bounds__(256) void k1_rowpass(const float* __restrict__ in,
                                                  float2* __restrict__ hp,
                                                  float* __restrict__ gray,
                                                  unsigned* __restrict__ cells) {
    __shared__ float gb[1056];              // swizzled 1024-float row buffer
    const int t = threadIdx.x;
    const int lane = t & 63, w = t >> 6;
    const int row = blockIdx.x;             // 0 .. NB*IMH-1
    const long long base = (long long)row * IMW;
    const int p0 = 4 * t;

    // ---- load 4 px RGB (dense float4), gray in f64 dot rounded to f32 ----
    const float4* p4 = (const float4*)(in + base * 3);
    float4 f0 = p4[3*t], f1 = p4[3*t+1], f2 = p4[3*t+2];
    float g0 = (float)((double)f0.x*W_R + (double)f0.y*W_G + (double)f0.z*W_B);
    float g1 = (float)((double)f0.w*W_R + (double)f1.x*W_G + (double)f1.y*W_B);
    float g2 = (float)((double)f1.z*W_R + (double)f1.w*W_G + (double)f2.x*W_B);
    float g3 = (float)((double)f2.y*W_R + (double)f2.z*W_G + (double)f2.w*W_B);

    gb[swz(p0+0)] = g0; gb[swz(p0+1)] = g1;
    gb[swz(p0+2)] = g2; gb[swz(p0+3)] = g3;
    ((float4*)(gray + base))[t] = make_float4(g0, g1, g2, g3);

    // per-wave min/max -> hierarchical atomic cells (wave-independent, no LDS)
    float lmin = fminf(fminf(g0, g1), fminf(g2, g3));
    float lmax = fmaxf(fmaxf(g0, g1), fmaxf(g2, g3));
    for (int off = 32; off; off >>= 1) {
        lmin = fminf(lmin, __shfl_down(lmin, off));
        lmax = fmaxf(lmax, __shfl_down(lmax, off));
    }
    if (lane == 0) {
        int cell = (4 * row + w) & (NCELL - 1);
        atomicMin(&cells[cell], __float_as_uint(lmin));
        atomicMax(&cells[NCELL + cell], __float_as_uint(lmax));
    }

    __syncthreads();   // halo reads below cross wave boundaries

    // ---- prologue: 51-tap window centered at p0, 3 independent f64 chains ----
    double s1a = 0, s1b = 0, s1c = 0, s2a = 0, s2b = 0, s2c = 0;
    #pragma unroll
    for (int i = 0; i < 51; i += 3) {
        double d0 = (double)gb[swz(refl(p0 - HALF + i + 0, IMW))];
        double d1 = (double)gb[swz(refl(p0 - HALF + i + 1, IMW))];
        double d2 = (double)gb[swz(refl(p0 - HALF + i + 2, IMW))];
        s1a += d0; s2a = fma(d0, d0, s2a);
        s1b += d1; s2b = fma(d1, d1, s2b);
        s1c += d2; s2c = fma(d2, d2, s2c);
    }
    double v1 = (s1a + s1b) + s1c;
    double v2 = (s2a + s2b) + s2c;

    // ---- 3-step slide over owned pixels, pack into two float4 stores ----
    float4 h01, h23;
    h01.x = (float)v1; h01.y = (float)v2;
    {
        double ga = (double)gb[swz(refl(p0 + 26, IMW))];
        double gs = (double)gb[swz(refl(p0 - 25, IMW))];
        v1 += ga - gs; v2 += ga * ga - gs * gs;
        h01.z = (float)v1; h01.w = (float)v2;
    }
    {
        double ga = (double)gb[swz(refl(p0 + 27, IMW))];
        double gs = (double)gb[swz(refl(p0 - 24, IMW))];
        v1 += ga - gs; v2 += ga * ga - gs * gs;
        h23.x = (float)v1; h23.y = (float)v2;
    }
    {
        double ga = (double)gb[swz(refl(p0 + 28, IMW))];
        double gs = (double)gb[swz(refl(p0 - 23, IMW))];
        v1 += ga - gs; v2 += ga * ga - gs * gs;
        h23.z = (float)v1; h23.w = (float)v2;
    }
    float4* o = (float4*)(hp + base + p0);   // (base+p0)*8B -> 32B aligned
    o[0] = h01;
    o[1] = h23;
}

// Column pass: 1 column/thread, vertical running 51-window over interleaved hp.
// Verbatim round-1 config (best measured): STRIP=32, 1024 blocks = 4 blocks/CU
// = 16 waves/CU. Strip-init re-reads ((51+64)/32 = 3.6 hp-rows/output-row) are
// largely L2/LLC hits (hp 67 MB + gray 33 MB ~ LLC-resident after k1).
// XCD-swizzled linear grid: batch = id&7 -> one image per XCD; consecutive ids
// walk y-strips so overlapping 51-row windows share L2.
// Sqrt/div-free Sauvola compare: g > m(1+0.2(s/r-1)) <=> A>0 && A^2 r^2 > 0.04 m^2 var.
__global__ __launch_bounds__(256) void k2_colpass(const float* __restrict__ gray,
                                                  const float2* __restrict__ hp,
                                                  const unsigned* __restrict__ cells,
                                                  float* __restrict__ out) {
    __shared__ double sr[2];
    const int t = threadIdx.x;
    if (t < 64) {
        unsigned mn = cells[t];
        unsigned mx = cells[NCELL + t];
        for (int off = 32; off; off >>= 1) {
            unsigned a = __shfl_down(mn, off);
            unsigned b = __shfl_down(mx, off);
            mn = (a < mn) ? a : mn;
            mx = (b > mx) ? b : mx;
        }
        if (t == 0) {
            sr[0] = (double)__uint_as_float(mn);
            sr[1] = (double)__uint_as_float(mx);
        }
    }
    __syncthreads();
    const double r  = 0.5 * (sr[1] - sr[0]);
    const double r2 = r * r;

    const int id   = blockIdx.x;          // 1024 blocks
    const int b    = id & 7;              // batch -> XCD
    const int rest = id >> 3;
    const int ys   = rest & 31;           // y-strip (consecutive on same XCD)
    const int xc   = rest >> 5;           // x quarter (0..3)
    const int x  = xc * 256 + t;          // 1 column per thread
    const int y0 = ys * STRIP;
    const long long ib = (long long)b * IMH * IMW;

    double vx = 0.0, vy = 0.0;            // {h1,h2} running vertical sums (f64 accum)
    #pragma unroll 8
    for (int j = -HALF; j <= HALF; j++) {
        int ry = refl(y0 + j, IMH);
        float2 h = hp[ib + (long long)ry * IMW + x];
        vx += (double)h.x; vy += (double)h.y;
    }

    #pragma unroll 8
    for (int y = y0; y < y0 + STRIP; y++) {
        long long pix = ib + (long long)y * IMW + x;
        double g = (double)gray[pix];

        double m  = vx * INV_AREA;
        double va = fmax(vy * INV_AREA - m * m, 0.0);
        double A  = g - 0.8 * m;
        int o = (A > 0.0) && (A * A * r2 > 0.04 * m * m * va);
        out[pix] = o ? 1.0f : 0.0f;

        int ra = refl(y + HALF + 1, IMH);
        int rs = refl(y - HALF, IMH);
        float2 ha = hp[ib + (long long)ra * IMW + x];
        float2 hs = hp[ib + (long long)rs * IMW + x];
        vx += (double)ha.x - (double)hs.x;
        vy += (double)ha.y - (double)hs.y;
    }
}

extern "C" void kernel_launch(void* const* d_in, const int* in_sizes, int n_in,
                              void* d_out, int out_size, void* d_ws, size_t ws_size,
                              hipStream_t stream) {
    const float* in = (const float*)d_in[0];
    float* out = (float*)d_out;

    unsigned* cells = (unsigned*)d_ws;                          // 2*64 u32
    float2* hp = (float2*)((char*)d_ws + 4096);                 // 67 MB interleaved {h1,h2}
    float* gray = (float*)((char*)d_ws + 4096
                           + (size_t)NB * IMH * IMW * sizeof(float2)); // 33.5 MB staged gray

    hipLaunchKernelGGL(k0_init, dim3(1), dim3(2 * NCELL), 0, stream, cells);
    hipLaunchKernelGGL(k1_rowpass, dim3(NB * IMH), dim3(256), 0, stream,
                       in, hp, gray, cells);
    hipLaunchKernelGGL(k2_colpass, dim3((IMW / 256) * (IMH / STRIP) * NB), dim3(256), 0, stream,
                       gray, hp, cells, out);
}

// Round 6
// 219.885 us; speedup vs baseline: 1.4443x; 1.4443x over previous
//
#include <hip/hip_runtime.h>

#define IMW 1024
#define IMH 1024
#define NB  8
#define HALF 25
#define STRIP 16
#define NCELL 64

#define W_R ((double)0.2989f)
#define W_G ((double)0.5870f)
#define W_B ((double)0.1140f)
#define INV_AREA (1.0 / 2601.0)

__device__ __forceinline__ int refl(int i, int n) {
    if (i < 0) i = -i;
    if (i >= n) i = 2 * n - 2 - i;
    return i;
}

// 51-window sum at pixel p from inclusive row cumsum C[0..IMW-1], reflect pad.
__device__ __forceinline__ double wsum(const double* __restrict__ C, int p) {
    int a = p + HALF; if (a > IMW - 1) a = IMW - 1;
    int b = p - HALF - 1;
    double s = C[a] - (b >= 0 ? C[b] : 0.0);
    if (p <= HALF - 1)      s += C[HALF - p] - C[0];                        // i<0 mirrored
    if (p >= IMW - HALF)    s += C[IMW - 2] - C[2*IMW - 2 - HALF - 1 - p];  // i>=IMW mirrored
    return s;
}

// init 64 min-cells (all-ones) and 64 max-cells (zero); g>=0 so f32 bit-order == uint order
__global__ void k0_init(unsigned* cells) {
    cells[threadIdx.x] = (threadIdx.x < NCELL) ? 0xFFFFFFFFu : 0u;
}

// One block per image row (r1-proven structure, 206.5us config). Cumsum of
// gray/gray^2 via register prefix + wave shuffle scan, 2-read window sums ->
// interleaved float2{h1,h2}. Min/max in f32 (r2-proven: halves bpermutes,
// candidate set == ref's f32 grays). Plain float2 hp stores (no packed-pair
// layout: that was r2's 2.1M-bank-conflict bug).
__global__ __launch_bounds__(256) void k1_rowpass(const float* __restrict__ in,
                                                  float2* __restrict__ hp,
                                                  float* __restrict__ gray,
                                                  unsigned* __restrict__ cells) {
    __shared__ double cs1[IMW];
    __shared__ double cs2[IMW];
    __shared__ double wt1[4], wt2[4];
    __shared__ float bmin[4], bmax[4];
    const int row = blockIdx.x;                 // 0 .. NB*IMH-1
    const long long base = (long long)row * IMW;
    const int t = threadIdx.x;
    const int lane = t & 63, w = t >> 6;

    // 4 consecutive pixels per thread = 12 floats = 3x float4 (48B, 16B-aligned)
    const float4* p4 = (const float4*)(in + base * 3);
    float4 f0 = p4[3*t], f1 = p4[3*t+1], f2 = p4[3*t+2];
    double g0 = (double)f0.x*W_R + (double)f0.y*W_G + (double)f0.z*W_B;
    double g1 = (double)f0.w*W_R + (double)f1.x*W_G + (double)f1.y*W_B;
    double g2 = (double)f1.z*W_R + (double)f1.w*W_G + (double)f2.x*W_B;
    double g3 = (double)f2.y*W_R + (double)f2.z*W_G + (double)f2.w*W_B;
    float gf0 = (float)g0, gf1 = (float)g1, gf2 = (float)g2, gf3 = (float)g3;

    // stage gray (f32) for k2: 16B coalesced store
    ((float4*)(gray + base))[t] = make_float4(gf0, gf1, gf2, gf3);

    double l1_0 = g0, l1_1 = l1_0 + g1, l1_2 = l1_1 + g2, l1_3 = l1_2 + g3;
    double l2_0 = g0*g0, l2_1 = l2_0 + g1*g1, l2_2 = l2_1 + g2*g2, l2_3 = l2_2 + g3*g3;

    // block min/max in f32 (1 bpermute per shuffle instead of 2)
    float lmin = fminf(fminf(gf0, gf1), fminf(gf2, gf3));
    float lmax = fmaxf(fmaxf(gf0, gf1), fmaxf(gf2, gf3));
    for (int off = 32; off; off >>= 1) {
        lmin = fminf(lmin, __shfl_down(lmin, off));
        lmax = fmaxf(lmax, __shfl_down(lmax, off));
    }
    if (lane == 0) { bmin[w] = lmin; bmax[w] = lmax; }

    // wave-level inclusive scan of per-thread totals
    double v1 = l1_3, v2 = l2_3;
    for (int off = 1; off < 64; off <<= 1) {
        double u1 = __shfl_up(v1, off);
        double u2 = __shfl_up(v2, off);
        if (lane >= off) { v1 += u1; v2 += u2; }
    }
    if (lane == 63) { wt1[w] = v1; wt2[w] = v2; }
    __syncthreads();
    double e1 = v1 - l1_3, e2 = v2 - l2_3;   // exclusive prefix within wave
    for (int j = 0; j < w; j++) { e1 += wt1[j]; e2 += wt2[j]; }

    // write inclusive cumsum, 16B stores
    double2* c1 = (double2*)&cs1[4*t];
    double2* c2 = (double2*)&cs2[4*t];
    c1[0] = make_double2(e1 + l1_0, e1 + l1_1);
    c1[1] = make_double2(e1 + l1_2, e1 + l1_3);
    c2[0] = make_double2(e2 + l2_0, e2 + l2_1);
    c2[1] = make_double2(e2 + l2_2, e2 + l2_3);

    if (t == 0) {
        float m0 = fminf(fminf(bmin[0], bmin[1]), fminf(bmin[2], bmin[3]));
        float m1 = fmaxf(fmaxf(bmax[0], bmax[1]), fmaxf(bmax[2], bmax[3]));
        int cell = row & (NCELL - 1);   // adjacent rows -> different cells
        atomicMin(&cells[cell], __float_as_uint(m0));
        atomicMax(&cells[NCELL + cell], __float_as_uint(m1));
    }
    __syncthreads();

    // interleaved {h1,h2} -> 8B/lane coalesced stores (f32 rounding only at store)
    for (int k = 0; k < 4; k++) {
        int p = t + 256 * k;
        hp[base + p] = make_float2((float)wsum(cs1, p), (float)wsum(cs2, p));
    }
}

// Column pass, 2 adjacent columns per thread: every hp access is one dense
// float4 (16B/lane, half the load instructions of 1-col float2) and each
// thread carries two independent f64 accumulator chains (2x MLP). 256-thread
// block covers 512 columns; STRIP=16 -> 1024 blocks = 4 blocks/CU = 16
// waves/CU (r1's measured-best occupancy) at r1's amortization in bytes
// ((51+32) float4 / 32 outputs = 2.6 loads/output). Per-column accumulation
// is instruction-identical to the r1-proven chain.
// XCD-swizzled linear grid: batch = id&7 -> one image per XCD; consecutive ids
// walk y-strips so overlapping 51-row windows share L2.
// Sqrt/div-free Sauvola compare: g > m(1+0.2(s/r-1)) <=> A>0 && A^2 r^2 > 0.04 m^2 var.
__global__ __launch_bounds__(256) void k2_colpass(const float* __restrict__ gray,
                                                  const float2* __restrict__ hp,
                                                  const unsigned* __restrict__ cells,
                                                  float* __restrict__ out) {
    __shared__ double sr[2];
    const int t = threadIdx.x;
    if (t < 64) {
        unsigned mn = cells[t];
        unsigned mx = cells[NCELL + t];
        for (int off = 32; off; off >>= 1) {
            unsigned a = __shfl_down(mn, off);
            unsigned b = __shfl_down(mx, off);
            mn = (a < mn) ? a : mn;
            mx = (b > mx) ? b : mx;
        }
        if (t == 0) {
            sr[0] = (double)__uint_as_float(mn);
            sr[1] = (double)__uint_as_float(mx);
        }
    }
    __syncthreads();
    const double r  = 0.5 * (sr[1] - sr[0]);
    const double r2 = r * r;

    const int id   = blockIdx.x;          // 1024 blocks
    const int b    = id & 7;              // batch -> XCD
    const int rest = id >> 3;
    const int ys   = rest & 63;           // y-strip of 16 rows (consecutive on same XCD)
    const int xh   = rest >> 6;           // x half (0..1)
    const int x  = xh * 512 + 2 * t;      // 2 adjacent columns per thread
    const int y0 = ys * STRIP;
    const long long ib = (long long)b * IMH * IMW;

    // running vertical sums: {h1,h2} for col x (a*) and col x+1 (b*)
    double ax = 0.0, ay = 0.0, bx = 0.0, by = 0.0;
    #pragma unroll 8
    for (int j = -HALF; j <= HALF; j++) {
        int ry = refl(y0 + j, IMH);
        float4 h = *(const float4*)&hp[ib + (long long)ry * IMW + x];
        ax += (double)h.x; ay += (double)h.y;
        bx += (double)h.z; by += (double)h.w;
    }

    #pragma unroll 8
    for (int y = y0; y < y0 + STRIP; y++) {
        long long pix = ib + (long long)y * IMW + x;
        float2 g2 = *(const float2*)&gray[pix];

        double m0  = ax * INV_AREA;
        double va0 = fmax(ay * INV_AREA - m0 * m0, 0.0);
        double A0  = (double)g2.x - 0.8 * m0;
        float o0 = ((A0 > 0.0) && (A0 * A0 * r2 > 0.04 * m0 * m0 * va0)) ? 1.0f : 0.0f;

        double m1  = bx * INV_AREA;
        double va1 = fmax(by * INV_AREA - m1 * m1, 0.0);
        double A1  = (double)g2.y - 0.8 * m1;
        float o1 = ((A1 > 0.0) && (A1 * A1 * r2 > 0.04 * m1 * m1 * va1)) ? 1.0f : 0.0f;

        *(float2*)&out[pix] = make_float2(o0, o1);

        int ra = refl(y + HALF + 1, IMH);
        int rs = refl(y - HALF, IMH);
        float4 ha = *(const float4*)&hp[ib + (long long)ra * IMW + x];
        float4 hs = *(const float4*)&hp[ib + (long long)rs * IMW + x];
        ax += (double)ha.x - (double)hs.x;
        ay += (double)ha.y - (double)hs.y;
        bx += (double)ha.z - (double)hs.z;
        by += (double)ha.w - (double)hs.w;
    }
}

extern "C" void kernel_launch(void* const* d_in, const int* in_sizes, int n_in,
                              void* d_out, int out_size, void* d_ws, size_t ws_size,
                              hipStream_t stream) {
    const float* in = (const float*)d_in[0];
    float* out = (float*)d_out;

    unsigned* cells = (unsigned*)d_ws;                          // 2*64 u32
    float2* hp = (float2*)((char*)d_ws + 4096);                 // 67 MB interleaved {h1,h2}
    float* gray = (float*)((char*)d_ws + 4096
                           + (size_t)NB * IMH * IMW * sizeof(float2)); // 33.5 MB staged gray

    hipLaunchKernelGGL(k0_init, dim3(1), dim3(2 * NCELL), 0, stream, cells);
    hipLaunchKernelGGL(k1_rowpass, dim3(NB * IMH), dim3(256), 0, stream,
                       in, hp, gray, cells);
    hipLaunchKernelGGL(k2_colpass, dim3(2 * (IMH / STRIP) * NB), dim3(256), 0, stream,
                       gray, hp, cells, out);
}

// Round 7
// 208.710 us; speedup vs baseline: 1.5216x; 1.0535x over previous
//
#include <hip/hip_runtime.h>

#define IMW 1024
#define IMH 1024
#define NB  8
#define HALF 25
#define STRIP 32
#define NCELL 64

#define W_R ((double)0.2989f)
#define W_G ((double)0.5870f)
#define W_B ((double)0.1140f)
#define INV_AREA (1.0 / 2601.0)

__device__ __forceinline__ int refl(int i, int n) {
    if (i < 0) i = -i;
    if (i >= n) i = 2 * n - 2 - i;
    return i;
}

// Padded LDS index for the cumsum arrays: +2 doubles per 8. Per-thread quad
// cs[4t..4t+3] stays contiguous at ci = 4t + 2*(t>>1) (start always even ->
// double2 stores remain 16B-aligned). Bank audit of the b128 writes over 16
// lanes: groups {0,8,20,28,8,16,28,4,16,24,4,12,24,0,12,20} -> exact 2-way
// (free, m136) vs the unpadded 8-way that produced the measured 1.05M
// SQ_LDS_BANK_CONFLICT. wsum reads spread equivalently.
__device__ __forceinline__ int pidx(int i) { return i + 2 * (i >> 3); }

// 51-window sum at pixel p from inclusive row cumsum C (padded layout).
__device__ __forceinline__ double wsum(const double* __restrict__ C, int p) {
    int a = p + HALF; if (a > IMW - 1) a = IMW - 1;
    int b = p - HALF - 1;
    double s = C[pidx(a)] - (b >= 0 ? C[pidx(b)] : 0.0);
    if (p <= HALF - 1)      s += C[pidx(HALF - p)] - C[pidx(0)];                        // i<0 mirrored
    if (p >= IMW - HALF)    s += C[pidx(IMW - 2)] - C[pidx(2*IMW - 2 - HALF - 1 - p)];  // i>=IMW mirrored
    return s;
}

// init 64 min-cells (all-ones) and 64 max-cells (zero); g>=0 so f32 bit-order == uint order
__global__ void k0_init(unsigned* cells) {
    cells[threadIdx.x] = (threadIdx.x < NCELL) ? 0xFFFFFFFFu : 0u;
}

// One block per image row (r1-proven structure). Cumsum of gray/gray^2 via
// register prefix + wave shuffle scan, 2-read window sums -> interleaved
// float2{h1,h2}. Min/max in f32. Only change vs the 206.5us champion: padded
// cumsum LDS layout (bit-identical values, 8-way -> 2-way banks).
__global__ __launch_bounds__(256) void k1_rowpass(const float* __restrict__ in,
                                                  float2* __restrict__ hp,
                                                  float* __restrict__ gray,
                                                  unsigned* __restrict__ cells) {
    __shared__ double cs1[1280];   // pidx(1023)=1277
    __shared__ double cs2[1280];
    __shared__ double wt1[4], wt2[4];
    __shared__ float bmin[4], bmax[4];
    const int row = blockIdx.x;                 // 0 .. NB*IMH-1
    const long long base = (long long)row * IMW;
    const int t = threadIdx.x;
    const int lane = t & 63, w = t >> 6;

    // 4 consecutive pixels per thread = 12 floats = 3x float4 (48B, 16B-aligned)
    const float4* p4 = (const float4*)(in + base * 3);
    float4 f0 = p4[3*t], f1 = p4[3*t+1], f2 = p4[3*t+2];
    double g0 = (double)f0.x*W_R + (double)f0.y*W_G + (double)f0.z*W_B;
    double g1 = (double)f0.w*W_R + (double)f1.x*W_G + (double)f1.y*W_B;
    double g2 = (double)f1.z*W_R + (double)f1.w*W_G + (double)f2.x*W_B;
    double g3 = (double)f2.y*W_R + (double)f2.z*W_G + (double)f2.w*W_B;
    float gf0 = (float)g0, gf1 = (float)g1, gf2 = (float)g2, gf3 = (float)g3;

    // stage gray (f32) for k2: 16B coalesced store
    ((float4*)(gray + base))[t] = make_float4(gf0, gf1, gf2, gf3);

    double l1_0 = g0, l1_1 = l1_0 + g1, l1_2 = l1_1 + g2, l1_3 = l1_2 + g3;
    double l2_0 = g0*g0, l2_1 = l2_0 + g1*g1, l2_2 = l2_1 + g2*g2, l2_3 = l2_2 + g3*g3;

    // block min/max in f32 (1 bpermute per shuffle instead of 2)
    float lmin = fminf(fminf(gf0, gf1), fminf(gf2, gf3));
    float lmax = fmaxf(fmaxf(gf0, gf1), fmaxf(gf2, gf3));
    for (int off = 32; off; off >>= 1) {
        lmin = fminf(lmin, __shfl_down(lmin, off));
        lmax = fmaxf(lmax, __shfl_down(lmax, off));
    }
    if (lane == 0) { bmin[w] = lmin; bmax[w] = lmax; }

    // wave-level inclusive scan of per-thread totals
    double v1 = l1_3, v2 = l2_3;
    for (int off = 1; off < 64; off <<= 1) {
        double u1 = __shfl_up(v1, off);
        double u2 = __shfl_up(v2, off);
        if (lane >= off) { v1 += u1; v2 += u2; }
    }
    if (lane == 63) { wt1[w] = v1; wt2[w] = v2; }
    __syncthreads();
    double e1 = v1 - l1_3, e2 = v2 - l2_3;   // exclusive prefix within wave
    for (int j = 0; j < w; j++) { e1 += wt1[j]; e2 += wt2[j]; }

    // write inclusive cumsum, 16B stores into padded layout
    const int ci = 4 * t + 2 * (t >> 1);     // == pidx(4t), quad contiguous, even
    double2* c1 = (double2*)&cs1[ci];
    double2* c2 = (double2*)&cs2[ci];
    c1[0] = make_double2(e1 + l1_0, e1 + l1_1);
    c1[1] = make_double2(e1 + l1_2, e1 + l1_3);
    c2[0] = make_double2(e2 + l2_0, e2 + l2_1);
    c2[1] = make_double2(e2 + l2_2, e2 + l2_3);

    if (t == 0) {
        float m0 = fminf(fminf(bmin[0], bmin[1]), fminf(bmin[2], bmin[3]));
        float m1 = fmaxf(fmaxf(bmax[0], bmax[1]), fmaxf(bmax[2], bmax[3]));
        int cell = row & (NCELL - 1);   // adjacent rows -> different cells
        atomicMin(&cells[cell], __float_as_uint(m0));
        atomicMax(&cells[NCELL + cell], __float_as_uint(m1));
    }
    __syncthreads();

    // interleaved {h1,h2} -> 8B/lane coalesced stores (f32 rounding only at store)
    for (int k = 0; k < 4; k++) {
        int p = t + 256 * k;
        hp[base + p] = make_float2((float)wsum(cs1, p), (float)wsum(cs2, p));
    }
}

// Column pass: 1 column/thread, vertical running 51-window over interleaved hp.
// r1-exact geometry (measured best: STRIP=32, 1024 blocks = 16 waves/CU,
// 28.8 B/output logical ~ 6.9 TB/s logical = knee of the byte/occupancy
// tradeoff; r6 proved k2 is BW-proportional to logical bytes here).
// NEW: block-uniform interior fast path for ys in [1,30] (30/32 strips):
// no refl, raw pointer increments, slide loads hoisted above the compare
// (side-effect-free; accumulation order unchanged -> bit-identical).
// Sqrt/div-free Sauvola compare: g > m(1+0.2(s/r-1)) <=> A>0 && A^2 r^2 > 0.04 m^2 var.
__global__ __launch_bounds__(256) void k2_colpass(const float* __restrict__ gray,
                                                  const float2* __restrict__ hp,
                                                  const unsigned* __restrict__ cells,
                                                  float* __restrict__ out) {
    __shared__ double sr[2];
    const int t = threadIdx.x;
    if (t < 64) {
        unsigned mn = cells[t];
        unsigned mx = cells[NCELL + t];
        for (int off = 32; off; off >>= 1) {
            unsigned a = __shfl_down(mn, off);
            unsigned b = __shfl_down(mx, off);
            mn = (a < mn) ? a : mn;
            mx = (b > mx) ? b : mx;
        }
        if (t == 0) {
            sr[0] = (double)__uint_as_float(mn);
            sr[1] = (double)__uint_as_float(mx);
        }
    }
    __syncthreads();
    const double r  = 0.5 * (sr[1] - sr[0]);
    const double r2 = r * r;

    const int id   = blockIdx.x;          // 1024 blocks
    const int b    = id & 7;              // batch -> XCD
    const int rest = id >> 3;
    const int ys   = rest & 31;           // y-strip (consecutive on same XCD)
    const int xc   = rest >> 5;           // x quarter (0..3)
    const int x  = xc * 256 + t;          // 1 column per thread
    const int y0 = ys * STRIP;
    const long long ib = (long long)b * IMH * IMW;

    double vx = 0.0, vy = 0.0;            // {h1,h2} running vertical sums (f64 accum)

    if (ys >= 1 && ys <= 30) {            // ---- interior: no reflection anywhere ----
        const float2* ph = hp + ib + (long long)(y0 - HALF) * IMW + x;
        #pragma unroll 17
        for (int j = 0; j < 51; j++) {    // same accumulation order as refl path
            float2 h = ph[0];
            vx += (double)h.x; vy += (double)h.y;
            ph += IMW;
        }
        const float2* pa = hp + ib + (long long)(y0 + HALF + 1) * IMW + x;
        const float2* ps = hp + ib + (long long)(y0 - HALF) * IMW + x;
        const float*  pg = gray + ib + (long long)y0 * IMW + x;
        float*        po = out  + ib + (long long)y0 * IMW + x;
        #pragma unroll 8
        for (int i = 0; i < STRIP; i++) {
            float2 ha = pa[0];            // hoisted slide loads (prefetch)
            float2 hs = ps[0];
            double g = (double)pg[0];

            double m  = vx * INV_AREA;
            double va = fmax(vy * INV_AREA - m * m, 0.0);
            double A  = g - 0.8 * m;
            int o = (A > 0.0) && (A * A * r2 > 0.04 * m * m * va);
            po[0] = o ? 1.0f : 0.0f;

            vx += (double)ha.x - (double)hs.x;   // same add order as refl path
            vy += (double)ha.y - (double)hs.y;
            pa += IMW; ps += IMW; pg += IMW; po += IMW;
        }
    } else {                              // ---- edge strips: original refl path ----
        #pragma unroll 8
        for (int j = -HALF; j <= HALF; j++) {
            int ry = refl(y0 + j, IMH);
            float2 h = hp[ib + (long long)ry * IMW + x];
            vx += (double)h.x; vy += (double)h.y;
        }
        #pragma unroll 8
        for (int y = y0; y < y0 + STRIP; y++) {
            long long pix = ib + (long long)y * IMW + x;
            double g = (double)gray[pix];

            double m  = vx * INV_AREA;
            double va = fmax(vy * INV_AREA - m * m, 0.0);
            double A  = g - 0.8 * m;
            int o = (A > 0.0) && (A * A * r2 > 0.04 * m * m * va);
            out[pix] = o ? 1.0f : 0.0f;

            int ra = refl(y + HALF + 1, IMH);
            int rs = refl(y - HALF, IMH);
            float2 ha = hp[ib + (long long)ra * IMW + x];
            float2 hs = hp[ib + (long long)rs * IMW + x];
            vx += (double)ha.x - (double)hs.x;
            vy += (double)ha.y - (double)hs.y;
        }
    }
}

extern "C" void kernel_launch(void* const* d_in, const int* in_sizes, int n_in,
                              void* d_out, int out_size, void* d_ws, size_t ws_size,
                              hipStream_t stream) {
    const float* in = (const float*)d_in[0];
    float* out = (float*)d_out;

    unsigned* cells = (unsigned*)d_ws;                          // 2*64 u32
    float2* hp = (float2*)((char*)d_ws + 4096);                 // 67 MB interleaved {h1,h2}
    float* gray = (float*)((char*)d_ws + 4096
                           + (size_t)NB * IMH * IMW * sizeof(float2)); // 33.5 MB staged gray

    hipLaunchKernelGGL(k0_init, dim3(1), dim3(2 * NCELL), 0, stream, cells);
    hipLaunchKernelGGL(k1_rowpass, dim3(NB * IMH), dim3(256), 0, stream,
                       in, hp, gray, cells);
    hipLaunchKernelGGL(k2_colpass, dim3((IMW / 256) * (IMH / STRIP) * NB), dim3(256), 0, stream,
                       gray, hp, cells, out);
}